// Round 9
// baseline (1122.779 us; speedup 1.0000x reference)
//
#include <hip/hip_runtime.h>

// gamma_{t+1}[j] = clip(sum_e w[e]*gamma_t[nbr[e]] + residual[j], 0, 1), 10 steps.
// R13 == R12 resubmit (container infra failure, no measurement).
// R12: dual-block-per-CU step (step_v3).
//  - 512-thread blocks, single 64KB LDS slice -> 2 blocks/CU, desynchronized,
//    mutually hide stage+barrier latency.
//  - gather loop loads uint4 (4 edges/lane/instr) with head/tail alignment.
//  - bucket-major contiguous ranges + branchless 4-row attribution (proven R11).
// Prep (count/scan/scatter) unchanged from R10/R11 (bit-identical pack).
// Edge pack u32: bits[27:14] = round(bl*2^21) (bl < 2^-7), bits[13:0] = nbr&0x3FFF.

#define BSHIFT 14
#define BSIZE  16384                   // floats per slice (64 KB)
#define LMASK  0x3FFFu
#define Q_SCALE 2097152.0f            // 2^21
#define Q_INV   4.76837158203125e-07f // 2^-21

typedef float floatx4 __attribute__((ext_vector_type(4)));
typedef int   intx4   __attribute__((ext_vector_type(4)));

__device__ __forceinline__ unsigned quantize(float b) {
    unsigned q = (unsigned)(b * Q_SCALE + 0.5f);
    return q > 16383u ? 16383u : q;
}
__device__ __forceinline__ float clip01(float x) { return fminf(fmaxf(x, 0.f), 1.f); }

// class mask: lanes whose 4-bit bucket id equals mine (4 ballots).
__device__ __forceinline__ unsigned long long class_mask(int b) {
    unsigned long long m = ~0ULL;
    #pragma unroll
    for (int k = 0; k < 4; ++k) {
        unsigned long long bb = __ballot((b >> k) & 1);
        m &= ((b >> k) & 1) ? bb : ~bb;
    }
    return m;
}

// row_ptr[j] = first edge index with seg >= j.
__global__ void build_rowptr(const int* __restrict__ seg, int* __restrict__ row_ptr,
                             int n_edges, int n_part) {
    int e = blockIdx.x * blockDim.x + threadIdx.x;
    if (e >= n_edges) return;
    int s = seg[e];
    int sprev = (e == 0) ? -1 : seg[e - 1];
    for (int j = sprev + 1; j <= s; ++j) row_ptr[j] = e;
    if (e == n_edges - 1)
        for (int j = s + 1; j <= n_part; ++j) row_ptr[j] = n_edges;
}

// P1: one wave per row -> per-bucket counts into OFF[b*n_part + row].
__global__ __launch_bounds__(256) void count_buckets(const int* __restrict__ nbr,
        const int* __restrict__ row_ptr, int* __restrict__ OFF,
        int n_part, int nb) {
    __shared__ int cnt[4][16];
    int wid  = threadIdx.x >> 6;
    int lane = threadIdx.x & 63;
    int row  = (blockIdx.x * 256 + threadIdx.x) >> 6;
    bool rv  = row < n_part;
    if (lane < 16) cnt[wid][lane] = 0;
    __syncthreads();
    if (rv) {
        int start = row_ptr[row], deg = row_ptr[row + 1] - start;
        for (int base = 0; base < deg; base += 64) {
            int j = base + lane;
            int b = (j < deg) ? (nbr[start + j] >> BSHIFT) : 15;
            unsigned long long m = class_mask(b);
            int rank = __popcll(m & ((1ULL << lane) - 1ULL));
            if (rank == 0 && b != 15) atomicAdd(&cnt[wid][b], __popcll(m));
        }
    }
    __syncthreads();
    if (rv && lane < nb) OFF[(size_t)lane * n_part + row] = cnt[wid][lane];
}

// P2a: per-chunk (8192 cells) sums.
__global__ __launch_bounds__(1024) void scan_part(const int* __restrict__ OFF,
        int* __restrict__ part, int cells) {
    __shared__ int wl[16];
    int base = blockIdx.x * 8192 + threadIdx.x * 8;
    int s = 0;
    if (base + 8 <= cells) {
        intx4 a = *(const intx4*)(OFF + base);
        intx4 b = *(const intx4*)(OFF + base + 4);
        s = a.x + a.y + a.z + a.w + b.x + b.y + b.z + b.w;
    } else {
        for (int k = 0; k < 8; ++k) if (base + k < cells) s += OFF[base + k];
    }
    int incl = s;
    #pragma unroll
    for (int d = 1; d < 64; d <<= 1) { int t = __shfl_up(incl, d); if ((threadIdx.x & 63) >= d) incl += t; }
    if ((threadIdx.x & 63) == 63) wl[threadIdx.x >> 6] = incl;
    __syncthreads();
    if (threadIdx.x == 0) {
        int tot = 0;
        for (int w = 0; w < 16; ++w) tot += wl[w];
        part[blockIdx.x] = tot;
    }
}

// P2b: exclusive scan of part[0..SB) in one block; also OFF[cells] = n_edges.
__global__ __launch_bounds__(1024) void scan_top(int* __restrict__ part,
        int* __restrict__ OFF, int SB, int cells, int n_edges) {
    __shared__ int a[1024];
    int v = (threadIdx.x < SB) ? part[threadIdx.x] : 0;
    a[threadIdx.x] = v;
    __syncthreads();
    for (int off = 1; off < 1024; off <<= 1) {
        int t = (threadIdx.x >= off) ? a[threadIdx.x - off] : 0;
        __syncthreads();
        a[threadIdx.x] += t;
        __syncthreads();
    }
    if (threadIdx.x < SB) part[threadIdx.x] = a[threadIdx.x] - v;
    if (threadIdx.x == 0) OFF[cells] = n_edges;
}

// P2c: in-place exclusive scan of each chunk, offset by part[blk].
__global__ __launch_bounds__(1024) void scan_apply(int* __restrict__ OFF,
        const int* __restrict__ part, int cells) {
    __shared__ int wl[16];
    int base = blockIdx.x * 8192 + threadIdx.x * 8;
    int v[8]; int s = 0;
    #pragma unroll
    for (int k = 0; k < 8; ++k) {
        v[k] = (base + k < cells) ? OFF[base + k] : 0;
        s += v[k];
    }
    int lane = threadIdx.x & 63, wid = threadIdx.x >> 6;
    int incl = s;
    #pragma unroll
    for (int d = 1; d < 64; d <<= 1) { int t = __shfl_up(incl, d); if (lane >= d) incl += t; }
    if (lane == 63) wl[wid] = incl;
    __syncthreads();
    if (threadIdx.x == 0) {
        int run = 0;
        for (int w = 0; w < 16; ++w) { int t = wl[w]; wl[w] = run; run += t; }
    }
    __syncthreads();
    int run = part[blockIdx.x] + wl[wid] + (incl - s);
    #pragma unroll
    for (int k = 0; k < 8; ++k) {
        if (base + k < cells) OFF[base + k] = run;
        run += v[k];
    }
}

// P3: one wave per row: class-mask rank scatter into bucket-major pack + residual/g1.
__global__ __launch_bounds__(256) void scatter_pack(const float* __restrict__ bl,
        const int* __restrict__ nbr, const int* __restrict__ row_ptr,
        const int* __restrict__ OFF, unsigned* __restrict__ pack,
        float* __restrict__ residual, float* __restrict__ g1,
        int n_part, int nb) {
    __shared__ int cur[4][16];
    int wid  = threadIdx.x >> 6;
    int lane = threadIdx.x & 63;
    int row  = (blockIdx.x * 256 + threadIdx.x) >> 6;
    bool rv  = row < n_part;
    if (lane < 16) cur[wid][lane] = (rv && lane < nb) ? OFF[(size_t)lane * n_part + row] : 0;
    __syncthreads();
    if (rv) {
        int start = row_ptr[row], deg = row_ptr[row + 1] - start;
        float accq = 0.f;
        for (int base = 0; base < deg; base += 64) {
            int j = base + lane;
            int nb_i = 0; float bv = 0.f; int b = 15;
            if (j < deg) { nb_i = nbr[start + j]; bv = bl[start + j]; b = nb_i >> BSHIFT; }
            unsigned long long m = class_mask(b);
            int rank = __popcll(m & ((1ULL << lane) - 1ULL));
            int leader_lane = (int)__ffsll((long long)m) - 1;
            int old = 0;
            if (rank == 0 && b != 15) old = atomicAdd(&cur[wid][b], __popcll(m));
            int basep = __shfl(old, leader_lane);
            if (b != 15) {
                unsigned q = quantize(bv);
                accq += (float)q;
                pack[basep + rank] = (q << 14) | ((unsigned)nb_i & LMASK);
            }
        }
        #pragma unroll
        for (int off = 32; off > 0; off >>= 1) accq += __shfl_down(accq, off);
        if (lane == 0) {
            float r = 1.0f - accq * Q_INV;
            residual[row] = r;
            g1[row] = clip01(r);
        }
    }
}

// Step: 512 threads, single 64KB slice (2 blocks/CU), 128 groups of 4 lanes,
// each group owns 3-4 consecutive rows; per phase walks one contiguous pack
// range with uint4 loads + branchless row attribution.
__global__ __launch_bounds__(512) void step_v3(const float* __restrict__ gamma_in,
        const unsigned* __restrict__ pack, const int* __restrict__ OFF,
        const float* __restrict__ residual, float* __restrict__ gamma_out,
        int n_part, int nb, int rpb) {
    __shared__ float s[BSIZE];
    int g   = threadIdx.x >> 2;            // 0..127
    int sub = threadIdx.x & 3;
    int r0  = blockIdx.x * rpb;
    int rlo = r0 + ((g * rpb) >> 7);       // balanced split of rpb rows over 128 groups
    int rhi = r0 + (((g + 1) * rpb) >> 7);
    if (rlo > n_part) rlo = n_part;
    if (rhi > n_part) rhi = n_part;
    bool gv = rlo < rhi;
    float acc0 = 0.f, acc1 = 0.f, acc2 = 0.f, acc3 = 0.f;

    for (int b = 0; b < nb; ++b) {
        int sbase  = b << BSHIFT;
        int scount = min(BSIZE, n_part - sbase);
        // stage: 512 threads x 32 floats = 16384
        #pragma unroll
        for (int i = 0; i < 8; ++i) {
            int fi = (threadIdx.x + 512 * i) * 4;
            floatx4 v;
            if (fi + 3 < scount) v = *(const floatx4*)(gamma_in + sbase + fi);
            else {
                floatx4 z = {0.f, 0.f, 0.f, 0.f};
                for (int e = 0; e < 4; ++e) if (fi + e < scount) z[e] = gamma_in[sbase + fi + e];
                v = z;
            }
            *(floatx4*)(s + fi) = v;
        }
        __syncthreads();
        if (gv) {
            int bn = b * n_part;
            int gs = OFF[bn + rlo];
            int ge = OFF[bn + rhi];
            int b1 = (rlo + 1 < rhi) ? OFF[bn + rlo + 1] : ge;
            int b2 = (rlo + 2 < rhi) ? OFF[bn + rlo + 2] : ge;
            int b3 = (rlo + 3 < rhi) ? OFF[bn + rlo + 3] : ge;
            int abase = (gs + 3) & ~3;
            // head: up to 3 unaligned edges, one per sub-lane
            {
                int e = gs + sub;
                if (e < abase && e < ge) {
                    unsigned p = pack[e];
                    float v = (float)(p >> 14) * s[p & LMASK];
                    acc0 += (e <  b1) ? v : 0.f;
                    acc1 += (e >= b1 && e < b2) ? v : 0.f;
                    acc2 += (e >= b2 && e < b3) ? v : 0.f;
                    acc3 += (e >= b3) ? v : 0.f;
                }
            }
            // aligned quads: lane sub owns quads at abase + 4*sub + 16k
            int i = abase + 4 * sub;
            for (; i + 3 < ge; i += 16) {
                uint4 p = *(const uint4*)(pack + i);
                float v0 = (float)(p.x >> 14) * s[p.x & LMASK];
                float v1 = (float)(p.y >> 14) * s[p.y & LMASK];
                float v2 = (float)(p.z >> 14) * s[p.z & LMASK];
                float v3 = (float)(p.w >> 14) * s[p.w & LMASK];
                int e = i;
                acc0 += ((e     <  b1) ? v0 : 0.f) + ((e + 1 <  b1) ? v1 : 0.f)
                      + ((e + 2 <  b1) ? v2 : 0.f) + ((e + 3 <  b1) ? v3 : 0.f);
                acc1 += ((e     >= b1 && e     < b2) ? v0 : 0.f) + ((e + 1 >= b1 && e + 1 < b2) ? v1 : 0.f)
                      + ((e + 2 >= b1 && e + 2 < b2) ? v2 : 0.f) + ((e + 3 >= b1 && e + 3 < b2) ? v3 : 0.f);
                acc2 += ((e     >= b2 && e     < b3) ? v0 : 0.f) + ((e + 1 >= b2 && e + 1 < b3) ? v1 : 0.f)
                      + ((e + 2 >= b2 && e + 2 < b3) ? v2 : 0.f) + ((e + 3 >= b2 && e + 3 < b3) ? v3 : 0.f);
                acc3 += ((e     >= b3) ? v0 : 0.f) + ((e + 1 >= b3) ? v1 : 0.f)
                      + ((e + 2 >= b3) ? v2 : 0.f) + ((e + 3 >= b3) ? v3 : 0.f);
            }
            // tail: partial quad owned by this lane
            for (int j = i; j < ge && j < i + 4; ++j) {
                unsigned p = pack[j];
                float v = (float)(p >> 14) * s[p & LMASK];
                acc0 += (j <  b1) ? v : 0.f;
                acc1 += (j >= b1 && j < b2) ? v : 0.f;
                acc2 += (j >= b2 && j < b3) ? v : 0.f;
                acc3 += (j >= b3) ? v : 0.f;
            }
        }
        __syncthreads();                   // slice reads done before next stage
    }
    acc0 += __shfl_down(acc0, 2); acc0 += __shfl_down(acc0, 1);
    acc1 += __shfl_down(acc1, 2); acc1 += __shfl_down(acc1, 1);
    acc2 += __shfl_down(acc2, 2); acc2 += __shfl_down(acc2, 1);
    acc3 += __shfl_down(acc3, 2); acc3 += __shfl_down(acc3, 1);
    if (sub == 0 && gv) {
        if (rlo     < rhi) gamma_out[rlo]     = clip01(acc0 * Q_INV + residual[rlo]);
        if (rlo + 1 < rhi) gamma_out[rlo + 1] = clip01(acc1 * Q_INV + residual[rlo + 1]);
        if (rlo + 2 < rhi) gamma_out[rlo + 2] = clip01(acc2 * Q_INV + residual[rlo + 2]);
        if (rlo + 3 < rhi) gamma_out[rlo + 3] = clip01(acc3 * Q_INV + residual[rlo + 3]);
    }
}

// ---------- fallback kernels (R4-proven path) ----------
#define NBR_MASK 0x3FFFFu
__global__ void pack_kernel(const float* __restrict__ bl, const int* __restrict__ nbr,
                            unsigned* __restrict__ pack, int n_edges) {
    int i = (blockIdx.x * blockDim.x + threadIdx.x) * 4;
    if (i + 3 < n_edges) {
        float4 b = *(const float4*)(bl + i);
        int4   v = *(const int4*)(nbr + i);
        uint4  o;
        o.x = (quantize(b.x) << 18) | (unsigned)v.x;
        o.y = (quantize(b.y) << 18) | (unsigned)v.y;
        o.z = (quantize(b.z) << 18) | (unsigned)v.z;
        o.w = (quantize(b.w) << 18) | (unsigned)v.w;
        *(uint4*)(pack + i) = o;
    } else {
        for (; i < n_edges; ++i) pack[i] = (quantize(bl[i]) << 18) | (unsigned)nbr[i];
    }
}

__global__ void rowsum_g1(const unsigned* __restrict__ pack,
                          const int* __restrict__ row_ptr,
                          float* __restrict__ residual, float* __restrict__ g1,
                          int n_part) {
    int idx  = blockIdx.x * blockDim.x + threadIdx.x;
    int row  = idx >> 6;
    int lane = threadIdx.x & 63;
    if (row >= n_part) return;
    int start = row_ptr[row], end = row_ptr[row + 1];
    float acc = 0.0f;
    for (int e = start + lane; e < end; e += 64) acc += (float)(pack[e] >> 18);
    #pragma unroll
    for (int off = 32; off > 0; off >>= 1) acc += __shfl_down(acc, off);
    if (lane == 0) {
        float r = 1.0f - acc * Q_INV;
        residual[row] = r;
        g1[row] = clip01(r);
    }
}

__global__ __launch_bounds__(256) void step4(const float* __restrict__ gamma_in,
                                             const unsigned* __restrict__ pack,
                                             const int* __restrict__ row_ptr,
                                             const float* __restrict__ residual,
                                             float* __restrict__ gamma_out, int n_part) {
    int tid = blockIdx.x * 256 + threadIdx.x;
    int row = tid >> 2;
    int sub = tid & 3;
    if (row >= n_part) return;
    int start = row_ptr[row], end = row_ptr[row + 1];
    float acc = 0.0f;
    int abase = (start + 3) & ~3;
    {
        int j = start + sub;
        if (j < abase && j < end) {
            unsigned p = pack[j];
            acc += (float)(p >> 18) * gamma_in[p & NBR_MASK];
        }
    }
    int i = abase + sub * 4;
    #pragma unroll 2
    for (; i + 3 < end; i += 16) {
        uint4 p = *(const uint4*)(pack + i);
        float g0 = gamma_in[p.x & NBR_MASK];
        float g1v = gamma_in[p.y & NBR_MASK];
        float g2 = gamma_in[p.z & NBR_MASK];
        float g3 = gamma_in[p.w & NBR_MASK];
        acc += (float)(p.x >> 18) * g0 + (float)(p.y >> 18) * g1v
             + (float)(p.z >> 18) * g2 + (float)(p.w >> 18) * g3;
    }
    for (int j = i; j < end && j < i + 4; ++j) {
        unsigned p = pack[j];
        acc += (float)(p >> 18) * gamma_in[p & NBR_MASK];
    }
    acc += __shfl_down(acc, 2);
    acc += __shfl_down(acc, 1);
    if (sub == 0) {
        float g = acc * Q_INV + residual[row];
        gamma_out[row] = clip01(g);
    }
}

__global__ __launch_bounds__(256) void step4_raw(const float* __restrict__ gamma_in,
                                                 const float* __restrict__ bl,
                                                 const int* __restrict__ nbr,
                                                 const int* __restrict__ row_ptr,
                                                 const float* __restrict__ residual,
                                                 float* __restrict__ gamma_out, int n_part) {
    int tid = blockIdx.x * 256 + threadIdx.x;
    int row = tid >> 2;
    int sub = tid & 3;
    if (row >= n_part) return;
    int start = row_ptr[row], end = row_ptr[row + 1];
    float acc = 0.0f;
    for (int j = start + sub; j < end; j += 4)
        acc += bl[j] * gamma_in[nbr[j]];
    acc += __shfl_down(acc, 2);
    acc += __shfl_down(acc, 1);
    if (sub == 0) {
        float g = acc + residual[row];
        gamma_out[row] = clip01(g);
    }
}

__global__ void residual_raw(const float* __restrict__ bl,
                             const int* __restrict__ row_ptr,
                             float* __restrict__ residual, float* __restrict__ g1,
                             int n_part) {
    int idx  = blockIdx.x * blockDim.x + threadIdx.x;
    int row  = idx >> 6;
    int lane = threadIdx.x & 63;
    if (row >= n_part) return;
    int start = row_ptr[row], end = row_ptr[row + 1];
    float acc = 0.0f;
    for (int e = start + lane; e < end; e += 64) acc += bl[e];
    #pragma unroll
    for (int off = 32; off > 0; off >>= 1) acc += __shfl_down(acc, off);
    if (lane == 0) {
        float r = 1.0f - acc;
        residual[row] = r;
        g1[row] = clip01(r);
    }
}

extern "C" void kernel_launch(void* const* d_in, const int* in_sizes, int n_in,
                              void* d_out, int out_size, void* d_ws, size_t ws_size,
                              hipStream_t stream) {
    const float* bl  = (const float*)d_in[1];
    const int*   nbr = (const int*)d_in[2];
    const int*   seg = (const int*)d_in[3];
    const int n_part  = in_sizes[0];
    const int n_edges = in_sizes[1];
    const int horizon = 10;
    float* gout = (float*)d_out;
    const int BLK = 256;

    auto align256 = [](size_t x) { return (x + 255) & ~(size_t)255; };
    char* ws = (char*)d_ws;
    size_t off = 0;
    int* row_ptr = (int*)(ws + off);      off += align256((size_t)(n_part + 1) * 4);
    float* residual = (float*)(ws + off); off += align256((size_t)n_part * 4);
    float* bufX = (float*)(ws + off);     off += align256((size_t)n_part * 4);
    float* bufY = (float*)(ws + off);     off += align256((size_t)n_part * 4);
    size_t off_base = off;

    int nb = (n_part + BSIZE - 1) >> BSHIFT;
    int cells = nb * n_part;
    int SB = (cells + 8191) / 8192;
    int rpb = (n_part + 511) / 512;        // rows per block for step_v3 (128 groups)

    // bucket-major layout: OFF (cells+1), part (<=1024), pack (n_edges)
    size_t off_off  = off_base;
    size_t part_off = off_off + align256(((size_t)cells + 1) * 4);
    size_t packb_off = part_off + align256(1024 * 4);
    size_t need_bm = packb_off + align256((size_t)(n_edges + 4) * 4);
    // fallback packed layout
    size_t packp_off = off_base;
    size_t need_packed = packp_off + align256((size_t)(n_edges + 4) * 4);

    bool use_bm = (nb >= 1) && (nb <= 15) && (SB <= 1024) && (rpb <= 512)
                  && (ws_size >= need_bm);
    bool use_packed = ws_size >= need_packed;

    build_rowptr<<<dim3((n_edges + BLK - 1) / BLK), dim3(BLK), 0, stream>>>(
        seg, row_ptr, n_edges, n_part);

    int wave_row_blocks = (n_part * 64 + BLK - 1) / BLK;
    int step_blocks     = (n_part * 4  + BLK - 1) / BLK;

    if (use_bm) {
        int* OFF = (int*)(ws + off_off);
        int* part = (int*)(ws + part_off);
        unsigned* pack = (unsigned*)(ws + packb_off);
        count_buckets<<<dim3(wave_row_blocks), dim3(BLK), 0, stream>>>(
            nbr, row_ptr, OFF, n_part, nb);
        scan_part<<<dim3(SB), dim3(1024), 0, stream>>>(OFF, part, cells);
        scan_top<<<dim3(1), dim3(1024), 0, stream>>>(part, OFF, SB, cells, n_edges);
        scan_apply<<<dim3(SB), dim3(1024), 0, stream>>>(OFF, part, cells);
        scatter_pack<<<dim3(wave_row_blocks), dim3(BLK), 0, stream>>>(
            bl, nbr, row_ptr, OFF, pack, residual, bufX, n_part, nb);
        int grid = (n_part + rpb - 1) / rpb;   // ~512 blocks, 2/CU
        const float* cur = bufX;               // gamma1 = clip(residual), gamma0 == 0
        for (int t = 2; t <= horizon; ++t) {
            float* dst = (t == horizon) ? gout : ((t & 1) ? bufX : bufY);
            step_v3<<<dim3(grid), dim3(512), 0, stream>>>(
                cur, pack, OFF, residual, dst, n_part, nb, rpb);
            cur = dst;
        }
        if (cur != gout)
            (void)hipMemcpyAsync(gout, cur, (size_t)n_part * 4, hipMemcpyDeviceToDevice, stream);
    } else if (use_packed) {
        unsigned* pack = (unsigned*)(ws + packp_off);
        int pack_threads = (n_edges + 3) / 4;
        pack_kernel<<<dim3((pack_threads + BLK - 1) / BLK), dim3(BLK), 0, stream>>>(
            bl, nbr, pack, n_edges);
        rowsum_g1<<<dim3(wave_row_blocks), dim3(BLK), 0, stream>>>(
            pack, row_ptr, residual, bufX, n_part);
        const float* cur = bufX;
        for (int t = 2; t <= horizon; ++t) {
            float* dst = (t == horizon) ? gout : ((t & 1) ? bufX : bufY);
            step4<<<dim3(step_blocks), dim3(BLK), 0, stream>>>(
                cur, pack, row_ptr, residual, dst, n_part);
            cur = dst;
        }
        if (cur != gout)
            (void)hipMemcpyAsync(gout, cur, (size_t)n_part * 4, hipMemcpyDeviceToDevice, stream);
    } else {
        residual_raw<<<dim3(wave_row_blocks), dim3(BLK), 0, stream>>>(
            bl, row_ptr, residual, bufX, n_part);
        const float* cur = bufX;
        for (int t = 2; t <= horizon; ++t) {
            float* dst = (t == horizon) ? gout : ((t & 1) ? bufX : bufY);
            step4_raw<<<dim3(step_blocks), dim3(BLK), 0, stream>>>(
                cur, bl, nbr, row_ptr, residual, dst, n_part);
            cur = dst;
        }
        if (cur != gout)
            (void)hipMemcpyAsync(gout, cur, (size_t)n_part * 4, hipMemcpyDeviceToDevice, stream);
    }
}

// Round 10
// 896.618 us; speedup vs baseline: 1.2522x; 1.2522x over previous
//
#include <hip/hip_runtime.h>

// gamma_{t+1}[j] = clip(sum_e w[e]*gamma_t[nbr[e]] + residual[j], 0, 1), 10 steps.
// R14: 128KB-slice step (step_v4) on the proven R11 structure.
//  - BSHIFT=15: 7 bucket phases (was 13) -> halves per-phase fixed cost
//    (barriers, wave-convergence imbalance, OFF dependency, first-touch latency).
//  - single 128KB LDS slice + register-prefetch of next slice (R11 pattern).
//  - uint4 pack loads in gather (4 edges/lane/instr).
//  - OFF boundaries for phase b+1 prefetched during phase b.
// Bucket pack u32: bits[31:15] = round(bl*2^22) (bl < 2^-7 -> <= 32768),
//                  bits[14:0] = nbr & 0x7FFF.  Fallback path keeps 14-bit enc.

#define BSHIFT 15
#define BSIZE  32768                   // floats per slice (128 KB)
#define LMASK  0x7FFFu
#define Q_SCALE 4194304.0f            // 2^22
#define Q_INV   2.384185791015625e-07f // 2^-22

typedef float floatx4 __attribute__((ext_vector_type(4)));
typedef int   intx4   __attribute__((ext_vector_type(4)));

__device__ __forceinline__ unsigned quantize17(float b) {
    unsigned q = (unsigned)(b * Q_SCALE + 0.5f);
    return q > 131071u ? 131071u : q;
}
__device__ __forceinline__ float clip01(float x) { return fminf(fmaxf(x, 0.f), 1.f); }

// class mask: lanes whose 4-bit bucket id equals mine (4 ballots).
__device__ __forceinline__ unsigned long long class_mask(int b) {
    unsigned long long m = ~0ULL;
    #pragma unroll
    for (int k = 0; k < 4; ++k) {
        unsigned long long bb = __ballot((b >> k) & 1);
        m &= ((b >> k) & 1) ? bb : ~bb;
    }
    return m;
}

// row_ptr[j] = first edge index with seg >= j.
__global__ void build_rowptr(const int* __restrict__ seg, int* __restrict__ row_ptr,
                             int n_edges, int n_part) {
    int e = blockIdx.x * blockDim.x + threadIdx.x;
    if (e >= n_edges) return;
    int s = seg[e];
    int sprev = (e == 0) ? -1 : seg[e - 1];
    for (int j = sprev + 1; j <= s; ++j) row_ptr[j] = e;
    if (e == n_edges - 1)
        for (int j = s + 1; j <= n_part; ++j) row_ptr[j] = n_edges;
}

// P1: one wave per row -> per-bucket counts into OFF[b*n_part + row].
__global__ __launch_bounds__(256) void count_buckets(const int* __restrict__ nbr,
        const int* __restrict__ row_ptr, int* __restrict__ OFF,
        int n_part, int nb) {
    __shared__ int cnt[4][16];
    int wid  = threadIdx.x >> 6;
    int lane = threadIdx.x & 63;
    int row  = (blockIdx.x * 256 + threadIdx.x) >> 6;
    bool rv  = row < n_part;
    if (lane < 16) cnt[wid][lane] = 0;
    __syncthreads();
    if (rv) {
        int start = row_ptr[row], deg = row_ptr[row + 1] - start;
        for (int base = 0; base < deg; base += 64) {
            int j = base + lane;
            int b = (j < deg) ? (nbr[start + j] >> BSHIFT) : 15;
            unsigned long long m = class_mask(b);
            int rank = __popcll(m & ((1ULL << lane) - 1ULL));
            if (rank == 0 && b != 15) atomicAdd(&cnt[wid][b], __popcll(m));
        }
    }
    __syncthreads();
    if (rv && lane < nb) OFF[(size_t)lane * n_part + row] = cnt[wid][lane];
}

// P2a: per-chunk (8192 cells) sums.
__global__ __launch_bounds__(1024) void scan_part(const int* __restrict__ OFF,
        int* __restrict__ part, int cells) {
    __shared__ int wl[16];
    int base = blockIdx.x * 8192 + threadIdx.x * 8;
    int s = 0;
    if (base + 8 <= cells) {
        intx4 a = *(const intx4*)(OFF + base);
        intx4 b = *(const intx4*)(OFF + base + 4);
        s = a.x + a.y + a.z + a.w + b.x + b.y + b.z + b.w;
    } else {
        for (int k = 0; k < 8; ++k) if (base + k < cells) s += OFF[base + k];
    }
    int incl = s;
    #pragma unroll
    for (int d = 1; d < 64; d <<= 1) { int t = __shfl_up(incl, d); if ((threadIdx.x & 63) >= d) incl += t; }
    if ((threadIdx.x & 63) == 63) wl[threadIdx.x >> 6] = incl;
    __syncthreads();
    if (threadIdx.x == 0) {
        int tot = 0;
        for (int w = 0; w < 16; ++w) tot += wl[w];
        part[blockIdx.x] = tot;
    }
}

// P2b: exclusive scan of part[0..SB) in one block; also OFF[cells] = n_edges.
__global__ __launch_bounds__(1024) void scan_top(int* __restrict__ part,
        int* __restrict__ OFF, int SB, int cells, int n_edges) {
    __shared__ int a[1024];
    int v = (threadIdx.x < SB) ? part[threadIdx.x] : 0;
    a[threadIdx.x] = v;
    __syncthreads();
    for (int off = 1; off < 1024; off <<= 1) {
        int t = (threadIdx.x >= off) ? a[threadIdx.x - off] : 0;
        __syncthreads();
        a[threadIdx.x] += t;
        __syncthreads();
    }
    if (threadIdx.x < SB) part[threadIdx.x] = a[threadIdx.x] - v;
    if (threadIdx.x == 0) OFF[cells] = n_edges;
}

// P2c: in-place exclusive scan of each chunk, offset by part[blk].
__global__ __launch_bounds__(1024) void scan_apply(int* __restrict__ OFF,
        const int* __restrict__ part, int cells) {
    __shared__ int wl[16];
    int base = blockIdx.x * 8192 + threadIdx.x * 8;
    int v[8]; int s = 0;
    #pragma unroll
    for (int k = 0; k < 8; ++k) {
        v[k] = (base + k < cells) ? OFF[base + k] : 0;
        s += v[k];
    }
    int lane = threadIdx.x & 63, wid = threadIdx.x >> 6;
    int incl = s;
    #pragma unroll
    for (int d = 1; d < 64; d <<= 1) { int t = __shfl_up(incl, d); if (lane >= d) incl += t; }
    if (lane == 63) wl[wid] = incl;
    __syncthreads();
    if (threadIdx.x == 0) {
        int run = 0;
        for (int w = 0; w < 16; ++w) { int t = wl[w]; wl[w] = run; run += t; }
    }
    __syncthreads();
    int run = part[blockIdx.x] + wl[wid] + (incl - s);
    #pragma unroll
    for (int k = 0; k < 8; ++k) {
        if (base + k < cells) OFF[base + k] = run;
        run += v[k];
    }
}

// P3: one wave per row: class-mask rank scatter into bucket-major pack + residual/g1.
__global__ __launch_bounds__(256) void scatter_pack(const float* __restrict__ bl,
        const int* __restrict__ nbr, const int* __restrict__ row_ptr,
        const int* __restrict__ OFF, unsigned* __restrict__ pack,
        float* __restrict__ residual, float* __restrict__ g1,
        int n_part, int nb) {
    __shared__ int cur[4][16];
    int wid  = threadIdx.x >> 6;
    int lane = threadIdx.x & 63;
    int row  = (blockIdx.x * 256 + threadIdx.x) >> 6;
    bool rv  = row < n_part;
    if (lane < 16) cur[wid][lane] = (rv && lane < nb) ? OFF[(size_t)lane * n_part + row] : 0;
    __syncthreads();
    if (rv) {
        int start = row_ptr[row], deg = row_ptr[row + 1] - start;
        float accq = 0.f;
        for (int base = 0; base < deg; base += 64) {
            int j = base + lane;
            int nb_i = 0; float bv = 0.f; int b = 15;
            if (j < deg) { nb_i = nbr[start + j]; bv = bl[start + j]; b = nb_i >> BSHIFT; }
            unsigned long long m = class_mask(b);
            int rank = __popcll(m & ((1ULL << lane) - 1ULL));
            int leader_lane = (int)__ffsll((long long)m) - 1;
            int old = 0;
            if (rank == 0 && b != 15) old = atomicAdd(&cur[wid][b], __popcll(m));
            int basep = __shfl(old, leader_lane);
            if (b != 15) {
                unsigned q = quantize17(bv);
                accq += (float)q;
                pack[basep + rank] = (q << 15) | ((unsigned)nb_i & LMASK);
            }
        }
        #pragma unroll
        for (int off = 32; off > 0; off >>= 1) accq += __shfl_down(accq, off);
        if (lane == 0) {
            float r = 1.0f - accq * Q_INV;
            residual[row] = r;
            g1[row] = clip01(r);
        }
    }
}

// Step: 1024 threads, single 128KB slice, register-prefetch of next slice +
// next OFF boundaries during gather; 256 groups x 3-4 consecutive rows; uint4
// pack loads with branchless row attribution.
__global__ __launch_bounds__(1024) void step_v4(const float* __restrict__ gamma_in,
        const unsigned* __restrict__ pack, const int* __restrict__ OFF,
        const float* __restrict__ residual, float* __restrict__ gamma_out,
        int n_part, int nb, int rpb) {
    __shared__ float s[BSIZE];
    int g   = threadIdx.x >> 2;            // 0..255
    int sub = threadIdx.x & 3;
    int r0  = blockIdx.x * rpb;
    int rlo = r0 + ((g * rpb) >> 8);
    int rhi = r0 + (((g + 1) * rpb) >> 8);
    if (rlo > n_part) rlo = n_part;
    if (rhi > n_part) rhi = n_part;
    bool gv = rlo < rhi;
    float acc0 = 0.f, acc1 = 0.f, acc2 = 0.f, acc3 = 0.f;

    floatx4 st[8];
    // prologue: stage slice 0 -> LDS
    {
        int scount = min(BSIZE, n_part);
        #pragma unroll
        for (int i = 0; i < 8; ++i) {
            int fi = (threadIdx.x + 1024 * i) * 4;
            floatx4 v;
            if (fi + 3 < scount) v = *(const floatx4*)(gamma_in + fi);
            else {
                floatx4 z = {0.f, 0.f, 0.f, 0.f};
                for (int e = 0; e < 4; ++e) if (fi + e < scount) z[e] = gamma_in[fi + e];
                v = z;
            }
            st[i] = v;
        }
        #pragma unroll
        for (int i = 0; i < 8; ++i)
            *(floatx4*)(&s[(threadIdx.x + 1024 * i) * 4]) = st[i];
    }
    // boundaries for phase 0
    int gs = 0, ge = 0, b1 = 0, b2 = 0, b3 = 0;
    if (gv) {
        gs = OFF[rlo];
        ge = OFF[rhi];
        b1 = (rlo + 1 < rhi) ? OFF[rlo + 1] : ge;
        b2 = (rlo + 2 < rhi) ? OFF[rlo + 2] : ge;
        b3 = (rlo + 3 < rhi) ? OFF[rlo + 3] : ge;
    }
    __syncthreads();

    for (int b = 0; b < nb; ++b) {
        bool have_next = (b + 1) < nb;
        if (have_next) {
            // issue next-slice loads (consumed after the barrier)
            int nsbase  = (b + 1) << BSHIFT;
            int nscount = min(BSIZE, n_part - nsbase);
            #pragma unroll
            for (int i = 0; i < 8; ++i) {
                int fi = (threadIdx.x + 1024 * i) * 4;
                floatx4 v;
                if (fi + 3 < nscount) v = *(const floatx4*)(gamma_in + nsbase + fi);
                else {
                    floatx4 z = {0.f, 0.f, 0.f, 0.f};
                    for (int e = 0; e < 4; ++e) if (fi + e < nscount) z[e] = gamma_in[nsbase + fi + e];
                    v = z;
                }
                st[i] = v;
            }
        }
        // prefetch next-phase boundaries
        int ngs = 0, nge = 0, nb1 = 0, nb2 = 0, nb3 = 0;
        if (have_next && gv) {
            int bn2 = (b + 1) * n_part;
            ngs = OFF[bn2 + rlo];
            nge = OFF[bn2 + rhi];
            nb1 = (rlo + 1 < rhi) ? OFF[bn2 + rlo + 1] : nge;
            nb2 = (rlo + 2 < rhi) ? OFF[bn2 + rlo + 2] : nge;
            nb3 = (rlo + 3 < rhi) ? OFF[bn2 + rlo + 3] : nge;
        }
        // gather phase on s
        if (gv) {
            int abase = (gs + 3) & ~3;
            {
                int e = gs + sub;
                if (e < abase && e < ge) {
                    unsigned p = pack[e];
                    float v = (float)(p >> 15) * s[p & LMASK];
                    acc0 += (e <  b1) ? v : 0.f;
                    acc1 += (e >= b1 && e < b2) ? v : 0.f;
                    acc2 += (e >= b2 && e < b3) ? v : 0.f;
                    acc3 += (e >= b3) ? v : 0.f;
                }
            }
            int i = abase + 4 * sub;
            for (; i + 3 < ge; i += 16) {
                uint4 p = *(const uint4*)(pack + i);
                float v0 = (float)(p.x >> 15) * s[p.x & LMASK];
                float v1 = (float)(p.y >> 15) * s[p.y & LMASK];
                float v2 = (float)(p.z >> 15) * s[p.z & LMASK];
                float v3 = (float)(p.w >> 15) * s[p.w & LMASK];
                int e = i;
                acc0 += ((e     <  b1) ? v0 : 0.f) + ((e + 1 <  b1) ? v1 : 0.f)
                      + ((e + 2 <  b1) ? v2 : 0.f) + ((e + 3 <  b1) ? v3 : 0.f);
                acc1 += ((e     >= b1 && e     < b2) ? v0 : 0.f) + ((e + 1 >= b1 && e + 1 < b2) ? v1 : 0.f)
                      + ((e + 2 >= b1 && e + 2 < b2) ? v2 : 0.f) + ((e + 3 >= b1 && e + 3 < b2) ? v3 : 0.f);
                acc2 += ((e     >= b2 && e     < b3) ? v0 : 0.f) + ((e + 1 >= b2 && e + 1 < b3) ? v1 : 0.f)
                      + ((e + 2 >= b2 && e + 2 < b3) ? v2 : 0.f) + ((e + 3 >= b2 && e + 3 < b3) ? v3 : 0.f);
                acc3 += ((e     >= b3) ? v0 : 0.f) + ((e + 1 >= b3) ? v1 : 0.f)
                      + ((e + 2 >= b3) ? v2 : 0.f) + ((e + 3 >= b3) ? v3 : 0.f);
            }
            for (int j = i; j < ge && j < i + 4; ++j) {
                unsigned p = pack[j];
                float v = (float)(p >> 15) * s[p & LMASK];
                acc0 += (j <  b1) ? v : 0.f;
                acc1 += (j >= b1 && j < b2) ? v : 0.f;
                acc2 += (j >= b2 && j < b3) ? v : 0.f;
                acc3 += (j >= b3) ? v : 0.f;
            }
        }
        __syncthreads();                   // all reads of s done
        if (have_next) {
            #pragma unroll
            for (int i = 0; i < 8; ++i)
                *(floatx4*)(&s[(threadIdx.x + 1024 * i) * 4]) = st[i];
            gs = ngs; ge = nge; b1 = nb1; b2 = nb2; b3 = nb3;
            __syncthreads();               // s ready for next phase
        }
    }
    acc0 += __shfl_down(acc0, 2); acc0 += __shfl_down(acc0, 1);
    acc1 += __shfl_down(acc1, 2); acc1 += __shfl_down(acc1, 1);
    acc2 += __shfl_down(acc2, 2); acc2 += __shfl_down(acc2, 1);
    acc3 += __shfl_down(acc3, 2); acc3 += __shfl_down(acc3, 1);
    if (sub == 0 && gv) {
        if (rlo     < rhi) gamma_out[rlo]     = clip01(acc0 * Q_INV + residual[rlo]);
        if (rlo + 1 < rhi) gamma_out[rlo + 1] = clip01(acc1 * Q_INV + residual[rlo + 1]);
        if (rlo + 2 < rhi) gamma_out[rlo + 2] = clip01(acc2 * Q_INV + residual[rlo + 2]);
        if (rlo + 3 < rhi) gamma_out[rlo + 3] = clip01(acc3 * Q_INV + residual[rlo + 3]);
    }
}

// ---------- fallback kernels (R4-proven path, 14-bit encoding) ----------
#define NBR_MASK 0x3FFFFu
#define Q_SCALE14 2097152.0f            // 2^21
#define Q_INV14   4.76837158203125e-07f // 2^-21
__device__ __forceinline__ unsigned quantize14(float b) {
    unsigned q = (unsigned)(b * Q_SCALE14 + 0.5f);
    return q > 16383u ? 16383u : q;
}

__global__ void pack_kernel(const float* __restrict__ bl, const int* __restrict__ nbr,
                            unsigned* __restrict__ pack, int n_edges) {
    int i = (blockIdx.x * blockDim.x + threadIdx.x) * 4;
    if (i + 3 < n_edges) {
        float4 b = *(const float4*)(bl + i);
        int4   v = *(const int4*)(nbr + i);
        uint4  o;
        o.x = (quantize14(b.x) << 18) | (unsigned)v.x;
        o.y = (quantize14(b.y) << 18) | (unsigned)v.y;
        o.z = (quantize14(b.z) << 18) | (unsigned)v.z;
        o.w = (quantize14(b.w) << 18) | (unsigned)v.w;
        *(uint4*)(pack + i) = o;
    } else {
        for (; i < n_edges; ++i) pack[i] = (quantize14(bl[i]) << 18) | (unsigned)nbr[i];
    }
}

__global__ void rowsum_g1(const unsigned* __restrict__ pack,
                          const int* __restrict__ row_ptr,
                          float* __restrict__ residual, float* __restrict__ g1,
                          int n_part) {
    int idx  = blockIdx.x * blockDim.x + threadIdx.x;
    int row  = idx >> 6;
    int lane = threadIdx.x & 63;
    if (row >= n_part) return;
    int start = row_ptr[row], end = row_ptr[row + 1];
    float acc = 0.0f;
    for (int e = start + lane; e < end; e += 64) acc += (float)(pack[e] >> 18);
    #pragma unroll
    for (int off = 32; off > 0; off >>= 1) acc += __shfl_down(acc, off);
    if (lane == 0) {
        float r = 1.0f - acc * Q_INV14;
        residual[row] = r;
        g1[row] = clip01(r);
    }
}

__global__ __launch_bounds__(256) void step4(const float* __restrict__ gamma_in,
                                             const unsigned* __restrict__ pack,
                                             const int* __restrict__ row_ptr,
                                             const float* __restrict__ residual,
                                             float* __restrict__ gamma_out, int n_part) {
    int tid = blockIdx.x * 256 + threadIdx.x;
    int row = tid >> 2;
    int sub = tid & 3;
    if (row >= n_part) return;
    int start = row_ptr[row], end = row_ptr[row + 1];
    float acc = 0.0f;
    int abase = (start + 3) & ~3;
    {
        int j = start + sub;
        if (j < abase && j < end) {
            unsigned p = pack[j];
            acc += (float)(p >> 18) * gamma_in[p & NBR_MASK];
        }
    }
    int i = abase + sub * 4;
    #pragma unroll 2
    for (; i + 3 < end; i += 16) {
        uint4 p = *(const uint4*)(pack + i);
        float g0 = gamma_in[p.x & NBR_MASK];
        float g1v = gamma_in[p.y & NBR_MASK];
        float g2 = gamma_in[p.z & NBR_MASK];
        float g3 = gamma_in[p.w & NBR_MASK];
        acc += (float)(p.x >> 18) * g0 + (float)(p.y >> 18) * g1v
             + (float)(p.z >> 18) * g2 + (float)(p.w >> 18) * g3;
    }
    for (int j = i; j < end && j < i + 4; ++j) {
        unsigned p = pack[j];
        acc += (float)(p >> 18) * gamma_in[p & NBR_MASK];
    }
    acc += __shfl_down(acc, 2);
    acc += __shfl_down(acc, 1);
    if (sub == 0) {
        float g = acc * Q_INV14 + residual[row];
        gamma_out[row] = clip01(g);
    }
}

__global__ __launch_bounds__(256) void step4_raw(const float* __restrict__ gamma_in,
                                                 const float* __restrict__ bl,
                                                 const int* __restrict__ nbr,
                                                 const int* __restrict__ row_ptr,
                                                 const float* __restrict__ residual,
                                                 float* __restrict__ gamma_out, int n_part) {
    int tid = blockIdx.x * 256 + threadIdx.x;
    int row = tid >> 2;
    int sub = tid & 3;
    if (row >= n_part) return;
    int start = row_ptr[row], end = row_ptr[row + 1];
    float acc = 0.0f;
    for (int j = start + sub; j < end; j += 4)
        acc += bl[j] * gamma_in[nbr[j]];
    acc += __shfl_down(acc, 2);
    acc += __shfl_down(acc, 1);
    if (sub == 0) {
        float g = acc + residual[row];
        gamma_out[row] = clip01(g);
    }
}

__global__ void residual_raw(const float* __restrict__ bl,
                             const int* __restrict__ row_ptr,
                             float* __restrict__ residual, float* __restrict__ g1,
                             int n_part) {
    int idx  = blockIdx.x * blockDim.x + threadIdx.x;
    int row  = idx >> 6;
    int lane = threadIdx.x & 63;
    if (row >= n_part) return;
    int start = row_ptr[row], end = row_ptr[row + 1];
    float acc = 0.0f;
    for (int e = start + lane; e < end; e += 64) acc += bl[e];
    #pragma unroll
    for (int off = 32; off > 0; off >>= 1) acc += __shfl_down(acc, off);
    if (lane == 0) {
        float r = 1.0f - acc;
        residual[row] = r;
        g1[row] = clip01(r);
    }
}

extern "C" void kernel_launch(void* const* d_in, const int* in_sizes, int n_in,
                              void* d_out, int out_size, void* d_ws, size_t ws_size,
                              hipStream_t stream) {
    const float* bl  = (const float*)d_in[1];
    const int*   nbr = (const int*)d_in[2];
    const int*   seg = (const int*)d_in[3];
    const int n_part  = in_sizes[0];
    const int n_edges = in_sizes[1];
    const int horizon = 10;
    float* gout = (float*)d_out;
    const int BLK = 256;

    auto align256 = [](size_t x) { return (x + 255) & ~(size_t)255; };
    char* ws = (char*)d_ws;
    size_t off = 0;
    int* row_ptr = (int*)(ws + off);      off += align256((size_t)(n_part + 1) * 4);
    float* residual = (float*)(ws + off); off += align256((size_t)n_part * 4);
    float* bufX = (float*)(ws + off);     off += align256((size_t)n_part * 4);
    float* bufY = (float*)(ws + off);     off += align256((size_t)n_part * 4);
    size_t off_base = off;

    int nb = (n_part + BSIZE - 1) >> BSHIFT;
    int cells = nb * n_part;
    int SB = (cells + 8191) / 8192;
    int rpb = (n_part + 255) / 256;        // rows per block (256 groups of 4 lanes)

    // bucket-major layout: OFF (cells+1), part (<=1024), pack (n_edges)
    size_t off_off  = off_base;
    size_t part_off = off_off + align256(((size_t)cells + 1) * 4);
    size_t packb_off = part_off + align256(1024 * 4);
    size_t need_bm = packb_off + align256((size_t)(n_edges + 4) * 4);
    // fallback packed layout
    size_t packp_off = off_base;
    size_t need_packed = packp_off + align256((size_t)(n_edges + 4) * 4);

    bool use_bm = (nb >= 1) && (nb <= 15) && (SB <= 1024) && (rpb <= 1024)
                  && (ws_size >= need_bm);
    bool use_packed = ws_size >= need_packed;

    build_rowptr<<<dim3((n_edges + BLK - 1) / BLK), dim3(BLK), 0, stream>>>(
        seg, row_ptr, n_edges, n_part);

    int wave_row_blocks = (n_part * 64 + BLK - 1) / BLK;
    int step_blocks     = (n_part * 4  + BLK - 1) / BLK;

    if (use_bm) {
        int* OFF = (int*)(ws + off_off);
        int* part = (int*)(ws + part_off);
        unsigned* pack = (unsigned*)(ws + packb_off);
        count_buckets<<<dim3(wave_row_blocks), dim3(BLK), 0, stream>>>(
            nbr, row_ptr, OFF, n_part, nb);
        scan_part<<<dim3(SB), dim3(1024), 0, stream>>>(OFF, part, cells);
        scan_top<<<dim3(1), dim3(1024), 0, stream>>>(part, OFF, SB, cells, n_edges);
        scan_apply<<<dim3(SB), dim3(1024), 0, stream>>>(OFF, part, cells);
        scatter_pack<<<dim3(wave_row_blocks), dim3(BLK), 0, stream>>>(
            bl, nbr, row_ptr, OFF, pack, residual, bufX, n_part, nb);
        int grid = (n_part + rpb - 1) / rpb;   // == 256 for this shape
        const float* cur = bufX;               // gamma1 = clip(residual), gamma0 == 0
        for (int t = 2; t <= horizon; ++t) {
            float* dst = (t == horizon) ? gout : ((t & 1) ? bufX : bufY);
            step_v4<<<dim3(grid), dim3(1024), 0, stream>>>(
                cur, pack, OFF, residual, dst, n_part, nb, rpb);
            cur = dst;
        }
        if (cur != gout)
            (void)hipMemcpyAsync(gout, cur, (size_t)n_part * 4, hipMemcpyDeviceToDevice, stream);
    } else if (use_packed) {
        unsigned* pack = (unsigned*)(ws + packp_off);
        int pack_threads = (n_edges + 3) / 4;
        pack_kernel<<<dim3((pack_threads + BLK - 1) / BLK), dim3(BLK), 0, stream>>>(
            bl, nbr, pack, n_edges);
        rowsum_g1<<<dim3(wave_row_blocks), dim3(BLK), 0, stream>>>(
            pack, row_ptr, residual, bufX, n_part);
        const float* cur = bufX;
        for (int t = 2; t <= horizon; ++t) {
            float* dst = (t == horizon) ? gout : ((t & 1) ? bufX : bufY);
            step4<<<dim3(step_blocks), dim3(BLK), 0, stream>>>(
                cur, pack, row_ptr, residual, dst, n_part);
            cur = dst;
        }
        if (cur != gout)
            (void)hipMemcpyAsync(gout, cur, (size_t)n_part * 4, hipMemcpyDeviceToDevice, stream);
    } else {
        residual_raw<<<dim3(wave_row_blocks), dim3(BLK), 0, stream>>>(
            bl, row_ptr, residual, bufX, n_part);
        const float* cur = bufX;
        for (int t = 2; t <= horizon; ++t) {
            float* dst = (t == horizon) ? gout : ((t & 1) ? bufX : bufY);
            step4_raw<<<dim3(step_blocks), dim3(BLK), 0, stream>>>(
                cur, bl, nbr, row_ptr, residual, dst, n_part);
            cur = dst;
        }
        if (cur != gout)
            (void)hipMemcpyAsync(gout, cur, (size_t)n_part * 4, hipMemcpyDeviceToDevice, stream);
    }
}